// Round 4
// baseline (87.835 us; speedup 1.0000x reference)
//
#include <hip/hip_runtime.h>
#include <hip/hip_bf16.h>

typedef __bf16 bf16_t;
typedef bf16_t bf16x2 __attribute__((ext_vector_type(2)));
typedef bf16_t bf16x8 __attribute__((ext_vector_type(8)));
typedef float  floatx4  __attribute__((ext_vector_type(4)));
typedef float  floatx16 __attribute__((ext_vector_type(16)));
typedef int    intx2    __attribute__((ext_vector_type(2)));

constexpr int B = 8, N = 2048, D = 64;

// --- fully-fused flash attention, transposed (S^T = K Q^T, O^T = V^T P^T) ---
// SINGLE dispatch, NO workspace: K/V are read as fp32 straight from the inputs
// and converted to MFMA fragment layout in-register each iteration (bitwise
// identical to the old prepass path). Each batch's K+V is 1 MB -> fully L1/L2
// resident across the 32 blocks that re-read it; the gather+cvt VALU overlaps
// MFMA. grid 256 = [qt(32)][b(8)], 512 thr = 8 kv-slice waves, QBLK=64 (two
// 32-row q-tiles share every K/V fragment). Q pre-scaled by 0.125*log2(e) so
// softmax exp is one v_exp_f32; positive scale preserves ==0 equality-mask
// semantics. Fragment mappings (match mfma_32x32x16 A/B layouts):
//   kreg[kd][lane]      = K[kv0 + (lane&31)][kd*16 + (lane>>5)*8 + j]
//   vreg[s2*2+dblk][ln] = V[kv0 + s2*16 + (ln>>5)*8 + j][dblk*32 + (ln&31)]
__global__ __launch_bounds__(512, 2)
void attn_fused_kernel(const float* __restrict__ q, const float* __restrict__ k,
                       const float* __restrict__ v, float* __restrict__ out) {
    __shared__ float o_buf[8 * 2048];   // 64 KB merge buffer (epilogue only)

    const int tid  = threadIdx.x;
    const int lane = tid & 63;
    const int cg   = tid >> 6;     // kv-slice wave: handles kvblk = it*8 + cg
    const int h    = lane >> 5;
    const int l31  = lane & 31;

    const int b  = blockIdx.x & 7;
    const int q0 = (blockIdx.x >> 3) * 64;

    const float* kb = k + (size_t)b * N * D;
    const float* vb = v + (size_t)b * N * D;

    // Q B-frags for both tiles, pre-scaled by 0.125*log2e then fp32->bf16
    constexpr float QSCALE = 0.125f * 1.4426950408889634f;
    bf16x8 qf[2][4];
    #pragma unroll
    for (int t = 0; t < 2; ++t) {
        const float* qp = q + ((size_t)b * N + q0 + t * 32 + l31) * D + h * 8;
        #pragma unroll
        for (int kd = 0; kd < 4; ++kd) {
            floatx4 f0 = *(const floatx4*)(qp + kd * 16);
            floatx4 f1 = *(const floatx4*)(qp + kd * 16 + 4);
            bf16x8 tt;
            #pragma unroll
            for (int j = 0; j < 4; ++j) {
                tt[j]     = (bf16_t)(f0[j] * QSCALE);
                tt[j + 4] = (bf16_t)(f1[j] * QSCALE);
            }
            qf[t][kd] = tt;
        }
    }

    floatx16 o_acc[2][2];
    #pragma unroll
    for (int t = 0; t < 2; ++t)
        #pragma unroll
        for (int d = 0; d < 2; ++d)
            #pragma unroll
            for (int i = 0; i < 16; ++i) o_acc[t][d][i] = 0.f;
    float l_run[2][2] = {{0.f, 0.f}, {0.f, 0.f}};   // [tile][split-acc]

    // K-frag loader: coalesced-ish floatx4 pairs + cvt (row = kv0+l31)
    auto load_k = [&](int kvb, bf16x8* kreg) {
        const float* kp = kb + ((size_t)(kvb * 32) + l31) * D + h * 8;
        #pragma unroll
        for (int kd = 0; kd < 4; ++kd) {
            floatx4 f0 = *(const floatx4*)(kp + kd * 16);
            floatx4 f1 = *(const floatx4*)(kp + kd * 16 + 4);
            bf16x8 o;
            #pragma unroll
            for (int j = 0; j < 4; ++j) { o[j] = (bf16_t)f0[j]; o[j + 4] = (bf16_t)f1[j]; }
            kreg[kd] = o;
        }
    };

    // prefetch kf frags for it=0 (kvblk = cg)
    bf16x8 kreg[4];
    load_k(cg, kreg);

    #pragma unroll 2
    for (int it = 0; it < 8; ++it) {
        const int kvb = it * 8 + cg;

        // V^T frags for THIS iter: stride-D gather (lane-coalesced along d) + cvt;
        // issued now, consumed after QK+softmax so latency hides under MFMA.
        bf16x8 vreg[4];
        #pragma unroll
        for (int s2 = 0; s2 < 2; ++s2)
            #pragma unroll
            for (int dblk = 0; dblk < 2; ++dblk) {
                const float* vp = vb + ((size_t)(kvb * 32 + s2 * 16 + h * 8)) * D + dblk * 32 + l31;
                bf16x8 o;
                #pragma unroll
                for (int j = 0; j < 8; ++j) o[j] = (bf16_t)vp[(size_t)j * D];
                vreg[s2 * 2 + dblk] = o;
            }

        // S^T(log2-domain) for both q-tiles, sharing kreg
        floatx16 s[2];
        #pragma unroll
        for (int t = 0; t < 2; ++t)
            #pragma unroll
            for (int i = 0; i < 16; ++i) s[t][i] = 0.f;
        __builtin_amdgcn_s_setprio(1);
        #pragma unroll
        for (int kd = 0; kd < 4; ++kd)
            s[0] = __builtin_amdgcn_mfma_f32_32x32x16_bf16(kreg[kd], qf[0][kd], s[0], 0, 0, 0);
        #pragma unroll
        for (int kd = 0; kd < 4; ++kd)
            s[1] = __builtin_amdgcn_mfma_f32_32x32x16_bf16(kreg[kd], qf[1][kd], s[1], 0, 0, 0);
        __builtin_amdgcn_s_setprio(0);

        // K frags for NEXT iter (SSA rename handles the WAR with the MFMAs above)
        if (it + 1 < 8) load_k((it + 1) * 8 + cg, kreg);

        #pragma unroll
        for (int t = 0; t < 2; ++t) {
            // equality-mask (attn==0 -> -inf -> weight 0) + exp2; pack bf16 pairs
            int q8[8];
            #pragma unroll
            for (int g = 0; g < 8; ++g) {
                union { int i; bf16x2 h2; } u;
                {
                    float x = s[t][2 * g + 0];
                    float p = (x == 0.0f) ? 0.0f : __builtin_amdgcn_exp2f(x);
                    l_run[t][0] += p;
                    u.h2[0] = (bf16_t)p;
                }
                {
                    float x = s[t][2 * g + 1];
                    float p = (x == 0.0f) ? 0.0f : __builtin_amdgcn_exp2f(x);
                    l_run[t][1] += p;
                    u.h2[1] = (bf16_t)p;
                }
                q8[g] = u.i;
            }

            // O^T += V^T P^T : A = V-frag, B = P^T-frag via permlane32_swap (the
            // two returned words are exactly the two B-frag halves)
            #pragma unroll
            for (int s2 = 0; s2 < 2; ++s2) {
                intx2 p02 = __builtin_amdgcn_permlane32_swap(q8[4 * s2 + 0], q8[4 * s2 + 2], false, false);
                intx2 p13 = __builtin_amdgcn_permlane32_swap(q8[4 * s2 + 1], q8[4 * s2 + 3], false, false);
                union { int i4[4]; bf16x8 v; } bf;
                bf.i4[0] = p02[0];
                bf.i4[1] = p13[0];
                bf.i4[2] = p02[1];
                bf.i4[3] = p13[1];
                __builtin_amdgcn_s_setprio(1);
                #pragma unroll
                for (int dblk = 0; dblk < 2; ++dblk)
                    o_acc[t][dblk] = __builtin_amdgcn_mfma_f32_32x32x16_bf16(vreg[s2 * 2 + dblk], bf.v,
                                                                             o_acc[t][dblk], 0, 0, 0);
                __builtin_amdgcn_s_setprio(0);
            }
        }
    }

    // complete each lane's denoms (partner half-wave holds the other 16 kv rows)
    #pragma unroll
    for (int t = 0; t < 2; ++t) {
        float l = l_run[t][0] + l_run[t][1];
        l += __shfl_xor(l, 32);
        l_run[t][0] = l;
    }

    // phase A: cross-wave denominator merge (first 512 floats of o_buf)
    if (h == 0) {
        o_buf[cg * 32 + l31]       = l_run[0][0];
        o_buf[256 + cg * 32 + l31] = l_run[1][0];
    }
    __syncthreads();
    float inv_l[2];
    {
        float s0 = 0.f, s1 = 0.f;
        #pragma unroll
        for (int w = 0; w < 8; ++w) {
            s0 += o_buf[w * 32 + l31];
            s1 += o_buf[256 + w * 32 + l31];
        }
        inv_l[0] = 1.0f / s0;
        inv_l[1] = 1.0f / s1;
    }

    // phases B/C: per-tile partial dump + parallel 8-way merge (buffer reused)
    #pragma unroll
    for (int t = 0; t < 2; ++t) {
        __syncthreads();   // protect o_buf reuse vs previous phase's reads
        {
            float* ob = o_buf + cg * 2048;
            #pragma unroll
            for (int dblk = 0; dblk < 2; ++dblk)
                #pragma unroll
                for (int i = 0; i < 16; ++i) {
                    const int d = (i & 3) + 8 * (i >> 2) + 4 * h + dblk * 32;
                    ob[d * 32 + l31] = o_acc[t][dblk][i];
                }
        }
        __syncthreads();
        {
            const int mdblk = cg >> 2, g = cg & 3;   // wave's merge d-group
            const int d0 = 8 * g + 4 * h + mdblk * 32;
            float* op = out + ((size_t)b * N + q0 + t * 32 + l31) * D;
            floatx4 o4;
            #pragma unroll
            for (int j = 0; j < 4; ++j) {
                float sum = 0.f;
                #pragma unroll
                for (int w = 0; w < 8; ++w)
                    sum += o_buf[w * 2048 + (d0 + j) * 32 + l31];
                o4[j] = sum * inv_l[t];
            }
            *(floatx4*)(op + d0) = o4;
        }
    }
}

extern "C" void kernel_launch(void* const* d_in, const int* in_sizes, int n_in,
                              void* d_out, int out_size, void* d_ws, size_t ws_size,
                              hipStream_t stream) {
    const float* q = (const float*)d_in[0];
    const float* k = (const float*)d_in[1];
    const float* v = (const float*)d_in[2];
    float* out = (float*)d_out;
    (void)d_ws; (void)ws_size;   // workspace-free: no prepass, no fill dependence

    hipLaunchKernelGGL(attn_fused_kernel, dim3(256), dim3(512), 0, stream, q, k, v, out);
}

// Round 5
// 80.657 us; speedup vs baseline: 1.0890x; 1.0890x over previous
//
#include <hip/hip_runtime.h>
#include <hip/hip_bf16.h>

typedef __bf16 bf16_t;
typedef bf16_t bf16x2 __attribute__((ext_vector_type(2)));
typedef bf16_t bf16x8 __attribute__((ext_vector_type(8)));
typedef float  floatx4  __attribute__((ext_vector_type(4)));
typedef float  floatx16 __attribute__((ext_vector_type(16)));
typedef int    intx2    __attribute__((ext_vector_type(2)));

constexpr int B = 8, N = 2048, D = 64;

// --- prepass: emit K and V in MFMA fragment order so the attention loop's
// loads are lane-contiguous (1KB coalesced per wave-load, no LDS staging).
// KF[b][kvblk][kd][lane][8]  = K[b][kvblk*32 + (lane&31)][kd*16 + (lane>>5)*8 + j]
// VF[b][kvblk][s2*2+dblk][lane][8] = V[b][kvblk*32 + s2*16 + (lane>>5)*8 + j][dblk*32 + (lane&31)]
// grid 512 = [kvblk(64)][b(8)], 256 thr.
// NOTE (R4 evidence): this buffer is load-bearing — fusing the transpose/cvt
// into the attn loop costs 32 scalar stride-256B loads per wave-iter (+9 us).
__global__ __launch_bounds__(256)
void prepass_kernel(const float* __restrict__ k, const float* __restrict__ v,
                    bf16_t* __restrict__ kf, bf16_t* __restrict__ vf) {
    __shared__ float t[32 * 65];
    const int tid = threadIdx.x;
    const int b   = blockIdx.x & 7;
    const int kvb = blockIdx.x >> 3;                       // 0..63
    const size_t inoff  = ((size_t)b * N + kvb * 32) * D;  // 32x64 fp32 chunk
    const size_t outoff = (size_t)(b * 64 + kvb) * 2048;   // 4x64x8 bf16 frags

    // K: coalesced read, fragment-order 16B write
    {
        const float* src = k + inoff;
        floatx4 f0 = *(const floatx4*)(src + tid * 8);
        floatx4 f1 = *(const floatx4*)(src + tid * 8 + 4);
        bf16x8 o;
        #pragma unroll
        for (int j = 0; j < 4; ++j) { o[j] = (bf16_t)f0[j]; o[j + 4] = (bf16_t)f1[j]; }
        const int rr = tid >> 3, kd = (tid >> 1) & 3, hh = tid & 1;
        *(bf16x8*)(kf + outoff + (size_t)kd * 512 + (hh * 32 + rr) * 8) = o;
    }
    // V: coalesced read -> padded LDS tile -> transposed gather -> coalesced frag write
    {
        const float* src = v + inoff;
        floatx4 f0 = *(const floatx4*)(src + tid * 8);
        floatx4 f1 = *(const floatx4*)(src + tid * 8 + 4);
        const int rr = tid >> 3, cc = (tid & 7) * 8;
        #pragma unroll
        for (int j = 0; j < 4; ++j) { t[rr * 65 + cc + j] = f0[j]; t[rr * 65 + cc + 4 + j] = f1[j]; }
        __syncthreads();
        const int s2 = tid >> 7, dblk = (tid >> 6) & 1, lane = tid & 63;
        const int hh = lane >> 5, l31 = lane & 31;
        bf16x8 o;
        #pragma unroll
        for (int j = 0; j < 8; ++j)
            o[j] = (bf16_t)t[(s2 * 16 + hh * 8 + j) * 65 + dblk * 32 + l31];
        *(bf16x8*)(vf + outoff + (size_t)(s2 * 2 + dblk) * 512 + lane * 8) = o;
    }
}

// --- flash attention, transposed (S^T = K Q^T, O^T = V^T P^T), fragment-direct ---
// grid 512 = [qt(64)][b(8)], 512 thr = 8 kv-slice waves. NO LDS / NO barriers in
// the loop. Q pre-scaled by 0.125*log2(e): S comes out already in log2 domain so
// the softmax exp is a single v_exp_f32 (exp2). Positive scale preserves the ==0
// equality-mask semantics. unroll 2 lets the compiler software-pipeline two
// iteration bodies (exp of i overlaps loads/MFMA of i+1).
// Measured-best structure (80.7 us total); R2 async-LDS ring, R3 QBLK=64 and
// R4 fused variants were all null-or-regression against it.
__global__ __launch_bounds__(512, 4)
void attn_kernel(const float* __restrict__ q, const bf16_t* __restrict__ kf,
                 const bf16_t* __restrict__ vf, float* __restrict__ out) {
    __shared__ float o_buf[8 * 2048];   // 64 KB: all 8 waves' O^T partials
    __shared__ float l_buf[8 * 32];     // 1 KB: denominators

    const int tid  = threadIdx.x;
    const int lane = tid & 63;
    const int cg   = tid >> 6;     // kv-slice wave: handles kvblk = it*8 + cg
    const int h    = lane >> 5;
    const int l31  = lane & 31;

    const int b  = blockIdx.x & 7;
    const int q0 = (blockIdx.x >> 3) * 32;

    const bf16_t* kfb = kf + (size_t)b * 131072;
    const bf16_t* vfb = vf + (size_t)b * 131072;

    // Q B-frags, pre-scaled by 0.125*log2e then fp32->bf16
    constexpr float QSCALE = 0.125f * 1.4426950408889634f;
    bf16x8 qf[4];
    {
        const float* qp = q + ((size_t)b * N + q0 + l31) * D + h * 8;
        #pragma unroll
        for (int kd = 0; kd < 4; ++kd) {
            floatx4 f0 = *(const floatx4*)(qp + kd * 16);
            floatx4 f1 = *(const floatx4*)(qp + kd * 16 + 4);
            bf16x8 t;
            #pragma unroll
            for (int j = 0; j < 4; ++j) {
                t[j]     = (bf16_t)(f0[j] * QSCALE);
                t[j + 4] = (bf16_t)(f1[j] * QSCALE);
            }
            qf[kd] = t;
        }
    }

    floatx16 o_acc[2];
    #pragma unroll
    for (int d = 0; d < 2; ++d)
        #pragma unroll
        for (int i = 0; i < 16; ++i) o_acc[d][i] = 0.f;
    float l_run0 = 0.f, l_run1 = 0.f;   // split accumulators: break serial add chain

    // prefetch kf for it=0 (kvblk = cg)
    bf16x8 kreg[4];
    #pragma unroll
    for (int kd = 0; kd < 4; ++kd)
        kreg[kd] = *(const bf16x8*)(kfb + (size_t)cg * 2048 + kd * 512 + lane * 8);

    #pragma unroll 2
    for (int it = 0; it < 8; ++it) {
        const size_t base = (size_t)(it * 8 + cg) * 2048;

        // vf for THIS iter: issued now, consumed after QK+softmax
        bf16x8 vreg[4];
        #pragma unroll
        for (int u = 0; u < 4; ++u)
            vreg[u] = *(const bf16x8*)(vfb + base + (size_t)u * 512 + lane * 8);

        // S^T(log2-domain) = K (Q*0.125*log2e)^T (32kv x 32q)
        floatx16 s;
        #pragma unroll
        for (int i = 0; i < 16; ++i) s[i] = 0.f;
        __builtin_amdgcn_s_setprio(1);
        #pragma unroll
        for (int kd = 0; kd < 4; ++kd)
            s = __builtin_amdgcn_mfma_f32_32x32x16_bf16(kreg[kd], qf[kd], s, 0, 0, 0);
        __builtin_amdgcn_s_setprio(0);

        // kf for NEXT iter (SSA rename handles the WAR with the MFMAs above)
        if (it + 1 < 8) {
            const size_t nbase = (size_t)((it + 1) * 8 + cg) * 2048;
            #pragma unroll
            for (int kd = 0; kd < 4; ++kd)
                kreg[kd] = *(const bf16x8*)(kfb + nbase + (size_t)kd * 512 + lane * 8);
        }

        // equality-mask (attn==0 -> -inf -> weight 0) + exp2; pack bf16 pairs
        int q8[8];
        #pragma unroll
        for (int g = 0; g < 8; ++g) {
            union { int i; bf16x2 h2; } u;
            {
                float x = s[2 * g + 0];
                float p = (x == 0.0f) ? 0.0f : __builtin_amdgcn_exp2f(x);
                l_run0 += p;
                u.h2[0] = (bf16_t)p;
            }
            {
                float x = s[2 * g + 1];
                float p = (x == 0.0f) ? 0.0f : __builtin_amdgcn_exp2f(x);
                l_run1 += p;
                u.h2[1] = (bf16_t)p;
            }
            q8[g] = u.i;
        }

        // O^T += V^T P^T : A = V-frag (global), B = P^T-frag via permlane32_swap.
        // The two returned words are exactly the two B-frag halves the old
        // shfl_xor+cndmask path built.
        #pragma unroll
        for (int s2 = 0; s2 < 2; ++s2) {
            intx2 p02 = __builtin_amdgcn_permlane32_swap(q8[4 * s2 + 0], q8[4 * s2 + 2], false, false);
            intx2 p13 = __builtin_amdgcn_permlane32_swap(q8[4 * s2 + 1], q8[4 * s2 + 3], false, false);
            union { int i4[4]; bf16x8 v; } bf;
            bf.i4[0] = p02[0];
            bf.i4[1] = p13[0];
            bf.i4[2] = p02[1];
            bf.i4[3] = p13[1];
            __builtin_amdgcn_s_setprio(1);
            #pragma unroll
            for (int dblk = 0; dblk < 2; ++dblk)
                o_acc[dblk] = __builtin_amdgcn_mfma_f32_32x32x16_bf16(vreg[s2 * 2 + dblk], bf.v,
                                                                      o_acc[dblk], 0, 0, 0);
            __builtin_amdgcn_s_setprio(0);
        }
    }

    // complete this lane's denom (partner half-wave holds the other 16 kv rows)
    float l_run = l_run0 + l_run1;
    l_run += __shfl_xor(l_run, 32);

    // ALL 8 waves dump partials; then the reduction is parallelized: wave cg owns
    // one (dblk,g) d-group of the 32x64 output.
    {
        float* ob = o_buf + cg * 2048;
        #pragma unroll
        for (int dblk = 0; dblk < 2; ++dblk)
            #pragma unroll
            for (int i = 0; i < 16; ++i) {
                const int d = (i & 3) + 8 * (i >> 2) + 4 * h + dblk * 32;
                ob[d * 32 + l31] = o_acc[dblk][i];
            }
        if (h == 0) l_buf[cg * 32 + l31] = l_run;
    }
    __syncthreads();
    {
        const int dblk = cg >> 2, g = cg & 3;
        const int d0 = 8 * g + 4 * h + dblk * 32;
        float lsum = 0.f;
        #pragma unroll
        for (int w = 0; w < 8; ++w) lsum += l_buf[w * 32 + l31];
        const float inv_l = 1.0f / lsum;
        floatx4 o4;
        #pragma unroll
        for (int j = 0; j < 4; ++j) {
            float sum = 0.f;
            #pragma unroll
            for (int w = 0; w < 8; ++w) sum += o_buf[w * 2048 + (d0 + j) * 32 + l31];
            o4[j] = sum * inv_l;
        }
        *(floatx4*)(out + ((size_t)b * N + q0 + l31) * D + d0) = o4;
    }
}

extern "C" void kernel_launch(void* const* d_in, const int* in_sizes, int n_in,
                              void* d_out, int out_size, void* d_ws, size_t ws_size,
                              hipStream_t stream) {
    const float* q = (const float*)d_in[0];
    const float* k = (const float*)d_in[1];
    const float* v = (const float*)d_in[2];
    float* out = (float*)d_out;
    bf16_t* kfrag = (bf16_t*)d_ws;                                    // 2 MB
    bf16_t* vfrag = (bf16_t*)((char*)d_ws + (size_t)B * N * D * 2);   // 2 MB

    hipLaunchKernelGGL(prepass_kernel, dim3(512), dim3(256), 0, stream, k, v, kfrag, vfrag);
    hipLaunchKernelGGL(attn_kernel, dim3(512), dim3(512), 0, stream, q, kfrag, vfrag, out);
}